// Round 10
// baseline (2483.956 us; speedup 1.0000x reference)
//
#include <hip/hip_runtime.h>
#include <hip/hip_bf16.h>

// GenericLSTM: B=64 T=2048 I=128 H=256, fp32 in/out.
// (1) pack W_h -> int8 MFMA A-fragments + per-col scales, (2) pack W_x ->
// bf16 MFMA fragment order, (3) MFMA GEMM g_x = inputs@W_x (f16), (4)
// persistent recurrent kernel: 1 WG/sample, 1024 thr (16 waves, 4/SIMD).
// Matvec on the matrix pipe (mfma_i32_16x16x64_i8, A=W^T frags register/
// AGPR-resident, B = h bytes broadcast: all 16 B-cols compute the same
// result). r10: tail compaction with SAFE barrier — owners read raw gates
// from sg directly (no shfl hop), branchless in-owner activations, running
// pointers for gx/out; barrier is plain __syncthreads() (r8/r9's inline-asm
// lgkmcnt+s_barrier coincided with 2x container failure; isolating it out).

#define B_ 64
#define T_ 2048
#define I_ 128
#define H_ 256
#define NC 1024  // 4 gates * H columns

typedef __attribute__((ext_vector_type(8))) short bf16x8;
typedef __attribute__((ext_vector_type(4))) float f32x4;
typedef __attribute__((ext_vector_type(4))) int i32x4;

static __device__ __forceinline__ unsigned short f2bf(float f) {
    unsigned u = __builtin_bit_cast(unsigned, f);
    u = (u + 0x7FFFu + ((u >> 16) & 1u)) >> 16;
    return (unsigned short)u;
}

static __device__ __forceinline__ float fastrcp(float x) {
    return __builtin_amdgcn_rcpf(x);
}

// ---------------- P1: W_h [4,256,256] f32 -> int8 packed directly as
// mfma_i32_16x16x64_i8 A-fragments (transposed: A[m=gatecol][k]) + per-col
// scale (scale already includes the 1/127 h dequant factor).
__global__ void pack_wh(const float* __restrict__ Wh, unsigned* __restrict__ afr,
                        float* __restrict__ sws) {
    int col = blockIdx.x;              // 0..1023 = g*256 + j
    int g = col >> 8, j = col & 255;
    int lane = threadIdx.x;            // 0..63, covers k = 4*lane..4*lane+3
    float v[4];
    float m = 0.f;
#pragma unroll
    for (int u = 0; u < 4; ++u) {
        int k = lane * 4 + u;
        v[u] = Wh[(g * H_ + k) * H_ + j];
        m = fmaxf(m, fabsf(v[u]));
    }
#pragma unroll
    for (int off = 32; off; off >>= 1) m = fmaxf(m, __shfl_xor(m, off));
    float mm = (m > 0.f) ? m : 1.f;
    float inv = 127.f / mm;
    unsigned pack = 0;
#pragma unroll
    for (int u = 0; u < 4; ++u) {
        int q = (int)rintf(v[u] * inv);
        q = max(-127, min(127, q));
        pack |= ((unsigned)(q & 255)) << (8 * u);
    }
    int fragid = ((j >> 4) * 4 + g) * 4 + (lane >> 4);
    int fl = (((lane & 15) >> 2) * 16) + (j & 15);
    int didx = (fragid * 64 + fl) * 4 + (lane & 3);
    afr[didx] = pack;
    if (lane == 0) sws[col] = mm / (127.f * 127.f);  // S_col/127
}

// ---------------- P2: W_x [4,128,256] f32 -> bf16 in MFMA-fragment order:
// Bfrag[((ki*4+q)*1024 + col)*8 + j] = W_x[g][k][h], k = (ki)*32 + q*8 + j.
__global__ void pack_wx(const float* __restrict__ Wx,
                        unsigned short* __restrict__ bxp) {
    int f = blockIdx.x * blockDim.x + threadIdx.x;  // 0..131071
    int j = f & 7;
    int col = (f >> 3) & 1023;
    int c16 = f >> 13;  // 0..15
    int k = (c16 >> 2) * 32 + (c16 & 3) * 8 + j;
    int g = col >> 8, h = col & 255;
    bxp[f] = f2bf(Wx[(g * I_ + k) * H_ + h]);
}

// ---------------- GEMM: g_x[row][col] = sum_k inputs[row][k] * W_x[k][col]
// rows = b*T+t (131072), cols = 1024, K = 128 (single shot, no k-loop).
// Output stored as f16.
__global__ __launch_bounds__(256) void gemm_gx(
    const float* __restrict__ A, const unsigned short* __restrict__ Bp,
    unsigned short* __restrict__ Cg) {
    __shared__ uint4 sm[4096];  // 64 KB: As = [0..2047], Bs = [2048..4095]
    int tid = threadIdx.x;
    int mt = blockIdx.x, nt = blockIdx.y;

    const float* Ab = A + (size_t)mt * 128 * I_;
    unsigned* dstA = (unsigned*)sm;
#pragma unroll
    for (int it = 0; it < 16; ++it) {
        int flat = it * 1024 + tid * 4;
        float4 a4 = *(const float4*)(Ab + flat);
        int m = flat >> 7, k0 = flat & 127;
        int c16 = k0 >> 3, j0 = k0 & 7;  // j0 in {0,4}
        unsigned lo = (unsigned)f2bf(a4.x) | ((unsigned)f2bf(a4.y) << 16);
        unsigned hi = (unsigned)f2bf(a4.z) | ((unsigned)f2bf(a4.w) << 16);
        int didx = ((c16 * 128 + m) * 16 + j0 * 2) >> 2;
        dstA[didx] = lo;
        dstA[didx + 1] = hi;
    }
    const uint4* Bq = (const uint4*)Bp;
#pragma unroll
    for (int it = 0; it < 8; ++it) {
        int chunk = it * 2 + (tid >> 7);
        int inner = tid & 127;
        sm[2048 + chunk * 128 + inner] = Bq[chunk * 1024 + nt * 128 + inner];
    }
    __syncthreads();

    int wid = tid >> 6, lane = tid & 63;
    int r = lane & 15, q = lane >> 4;
    int mw = (wid & 1) * 64, nw = (wid >> 1) * 64;
    f32x4 acc[4][4] = {};
#pragma unroll
    for (int ki = 0; ki < 4; ++ki) {
        bf16x8 af[4], bfr[4];
#pragma unroll
        for (int x = 0; x < 4; ++x) {
            af[x] = __builtin_bit_cast(bf16x8,
                                       sm[(ki * 4 + q) * 128 + mw + x * 16 + r]);
            bfr[x] = __builtin_bit_cast(
                bf16x8, sm[2048 + (ki * 4 + q) * 128 + nw + x * 16 + r]);
        }
#pragma unroll
        for (int x = 0; x < 4; ++x)
#pragma unroll
            for (int y = 0; y < 4; ++y)
                acc[x][y] = __builtin_amdgcn_mfma_f32_16x16x32_bf16(
                    af[x], bfr[y], acc[x][y], 0, 0, 0);
    }
    __syncthreads();

    _Float16* ct = (_Float16*)sm;
#pragma unroll
    for (int x = 0; x < 4; ++x)
#pragma unroll
        for (int y = 0; y < 4; ++y)
#pragma unroll
            for (int g2 = 0; g2 < 4; ++g2) {
                int row = mw + x * 16 + q * 4 + g2;
                int colc = nw + y * 16 + r;
                ct[row * 128 + colc] = (_Float16)acc[x][y][g2];
            }
    __syncthreads();
    int m = tid >> 1, half = tid & 1;
    const uint4* src = (const uint4*)sm;
    uint4* dstg =
        (uint4*)(Cg + ((size_t)(mt * 128 + m) * NC + nt * 128 + half * 64));
#pragma unroll
    for (int i = 0; i < 8; ++i) dstg[i] = src[m * 16 + half * 8 + i];
}

// ---------------- Recurrent kernel: 64 WGs (1/sample) x 1024 threads.
// Wave w covers H-cols j = w*16..w*16+15, all 4 gates. A-frags in regs/AGPRs;
// per step: 4x ds_read_b128 B-frag + 16 MFMA; writers (lane&15==0) dump raw D
// to sg; owners (lanes 0..15) read 4 raw gates from sg, branchless
// activations + c/h in-lane; plain __syncthreads barrier.
__global__ __launch_bounds__(1024, 4) void lstm_rec(
    const unsigned short* __restrict__ gx, const uint4* __restrict__ afr,
    const float* __restrict__ sws, const float* __restrict__ bias,
    float* __restrict__ out) {
    int b = blockIdx.x, tid = threadIdx.x;
    int w = tid >> 6;          // wave 0..15
    int lane = tid & 63;
    int jj = lane & 15;
    int j = w * 16 + jj;       // H column this lane tracks (owners: lane<16)

    // A-fragments: af[gate][kt], 16 x uint4, loop-invariant.
    uint4 af[4][4];
#pragma unroll
    for (int gg = 0; gg < 4; ++gg)
#pragma unroll
        for (int kt = 0; kt < 4; ++kt)
            af[gg][kt] = afr[(((w * 4 + gg) * 4) + kt) * 64 + lane];

    // Owner-side per-gate scales/biases for column j (loaded by all lanes
    // with jj so no divergence; only owners use them).
    float sc4[4], bb4[4];
#pragma unroll
    for (int gg = 0; gg < 4; ++gg) {
        sc4[gg] = sws[gg * H_ + j];
        bb4[gg] = bias[gg * H_ + j];
    }

    __shared__ uint4 hq[2][16];                // 256 int8 h, double buffered
    __shared__ __align__(16) int sg[16 * 64];  // per-wave raw D redistribute
    if (tid < 16) hq[0][tid] = (uint4){0u, 0u, 0u, 0u};
    __syncthreads();

    float c = 0.f;               // live only in owner lanes (lane<16)
    const _Float16* gxh = (const _Float16*)gx;
    size_t rowbase = (size_t)b * T_;

    // Running pointers (gate g at imm offset g*256 f16 = g*512 bytes).
    const _Float16* gxp = gxh + rowbase * NC + j;
    float gv0 = (float)gxp[0], gv1 = (float)gxp[256];
    float gv2 = (float)gxp[512], gv3 = (float)gxp[768];
    gxp += NC;  // points at row rowbase+1
    float* outp = out + rowbase * H_ + j;

    for (int t = 0; t < T_; ++t) {
        // prefetch next row's g_x (at t=T_-1 re-reads the last row; unused)
        float nv0 = (float)gxp[0], nv1 = (float)gxp[256];
        float nv2 = (float)gxp[512], nv3 = (float)gxp[768];
        gxp += (t < T_ - 2) ? NC : 0;

        // B-frag: every lane supplies h bytes for its k-block (lane>>4);
        // all 16 B-columns compute the same (correct) result.
        const char* hb = (const char*)hq[t & 1];
        i32x4 d0 = {0, 0, 0, 0}, d1 = {0, 0, 0, 0};
        i32x4 d2 = {0, 0, 0, 0}, d3 = {0, 0, 0, 0};
#pragma unroll
        for (int kt = 0; kt < 4; ++kt) {
            uint4 bf = *(const uint4*)(hb + kt * 64 + ((lane >> 4) << 4));
            i32x4 bfi = __builtin_bit_cast(i32x4, bf);
            d0 = __builtin_amdgcn_mfma_i32_16x16x64_i8(
                __builtin_bit_cast(i32x4, af[0][kt]), bfi, d0, 0, 0, 0);
            d1 = __builtin_amdgcn_mfma_i32_16x16x64_i8(
                __builtin_bit_cast(i32x4, af[1][kt]), bfi, d1, 0, 0, 0);
            d2 = __builtin_amdgcn_mfma_i32_16x16x64_i8(
                __builtin_bit_cast(i32x4, af[2][kt]), bfi, d2, 0, 0, 0);
            d3 = __builtin_amdgcn_mfma_i32_16x16x64_i8(
                __builtin_bit_cast(i32x4, af[3][kt]), bfi, d3, 0, 0, 0);
        }
        // D: col=lane&15, row=(lane>>4)*4+reg. Writers: col-0 lanes.
        // sg[w*64 + gate*16 + row] = raw pre-act.
        if ((lane & 15) == 0) {
            int base = w * 64 + (lane >> 4) * 4;
            *(i32x4*)&sg[base + 0 * 16] = d0;
            *(i32x4*)&sg[base + 1 * 16] = d1;
            *(i32x4*)&sg[base + 2 * 16] = d2;
            *(i32x4*)&sg[base + 3 * 16] = d3;
        }
        __builtin_amdgcn_sched_barrier(0);  // keep reads after in-wave writes

        if (lane < 16) {  // owners: all 4 gates of column j, fully in-lane
            int gi0 = sg[w * 64 + 0 * 16 + lane];
            int gi1 = sg[w * 64 + 1 * 16 + lane];
            int gi2 = sg[w * 64 + 2 * 16 + lane];
            int gi3 = sg[w * 64 + 3 * 16 + lane];
            float p0 = (float)gi0 * sc4[0] + gv0 + bb4[0];
            float p1 = (float)gi1 * sc4[1] + gv1 + bb4[1];
            float p2 = (float)gi2 * sc4[2] + gv2 + bb4[2];
            float p3 = (float)gi3 * sc4[3] + gv3 + bb4[3];
            float ig = fastrcp(1.f + __expf(-p0));
            float fg = fastrcp(1.f + __expf(-p1));
            float gg = 2.f * fastrcp(1.f + __expf(-2.f * p2)) - 1.f;
            float og = fastrcp(1.f + __expf(-p3));
            c = fg * c + ig * gg;
            float th = 2.f * fastrcp(1.f + __expf(-2.f * c)) - 1.f;
            float h = og * th;
            *outp = h;
            int qv = (int)rintf(h * 127.f);
            ((signed char*)hq[(t + 1) & 1])[j] = (signed char)qv;
        }
        outp += H_;

        __syncthreads();  // h buffer (t+1) complete before next step reads

        gv0 = nv0; gv1 = nv1; gv2 = nv2; gv3 = nv3;
    }
}

extern "C" void kernel_launch(void* const* d_in, const int* in_sizes, int n_in,
                              void* d_out, int out_size, void* d_ws,
                              size_t ws_size, hipStream_t stream) {
    const float* inputs = (const float*)d_in[0];
    const float* Wx = (const float*)d_in[1];
    const float* Wh = (const float*)d_in[2];
    const float* bias = (const float*)d_in[3];
    float* out = (float*)d_out;

    char* ws = (char*)d_ws;
    unsigned short* gxbuf = (unsigned short*)ws;   // 131072*1024 f16 = 256 MiB
    size_t off = (size_t)B_ * T_ * NC * 2;
    unsigned* afr = (unsigned*)(ws + off);         // 256 KiB int8 W_h A-frags
    off += (size_t)NC * 64 * 4;
    float* sws = (float*)(ws + off);               // 4 KiB scales
    off += (size_t)NC * 4;
    unsigned short* bxp = (unsigned short*)(ws + off);  // 256 KiB bf16 W_x
    off += (size_t)I_ * NC * 2;

    pack_wh<<<NC, 64, 0, stream>>>(Wh, afr, sws);
    pack_wx<<<(I_ * NC) / 256, 256, 0, stream>>>(Wx, bxp);
    gemm_gx<<<dim3((B_ * T_) / 128, NC / 128), 256, 0, stream>>>(inputs, bxp,
                                                                 gxbuf);
    lstm_rec<<<B_, 1024, 0, stream>>>(gxbuf, (const uint4*)afr, sws, bias, out);
}